// Round 1
// baseline (418.418 us; speedup 1.0000x reference)
//
#include <hip/hip_runtime.h>
#include <math.h>

#define C    32      // attention dim (q_dim // r1)
#define QD   64      // x1 channels
#define VD   64      // output channels
#define BLK  512     // sliding window block length
#define HALF 256
#define WW   1024    // window width = BLK + 2*HALF
#define CK   128     // keys per LDS chunk
#define QT   128     // queries per workgroup

// ---------------- kernel 1: 1x1-conv QKV projection ----------------
// q/k/v stored position-major: qT[l*32+o]. q pre-scaled by 1/sqrt(32).
__global__ __launch_bounds__(256) void qkv_proj(
    const float* __restrict__ x1,
    const float* __restrict__ Wq, const float* __restrict__ bq,
    const float* __restrict__ Wk, const float* __restrict__ bk,
    const float* __restrict__ Wv, const float* __restrict__ bv,
    float* __restrict__ qT, float* __restrict__ kT, float* __restrict__ vT,
    int L)
{
    __shared__ float sWq[C * QD], sWk[C * QD], sWv[C * QD];
    __shared__ float sb[3 * C];
    const int tid = threadIdx.x;
    for (int i = tid; i < C * QD; i += 256) {
        sWq[i] = Wq[i]; sWk[i] = Wk[i]; sWv[i] = Wv[i];
    }
    if (tid < C) { sb[tid] = bq[tid]; sb[C + tid] = bk[tid]; sb[2 * C + tid] = bv[tid]; }
    __syncthreads();

    const int l = blockIdx.x * 256 + tid;
    if (l >= L) return;

    float qa[C], ka[C], va[C];
    #pragma unroll
    for (int o = 0; o < C; ++o) { qa[o] = 0.f; ka[o] = 0.f; va[o] = 0.f; }

    #pragma unroll 2
    for (int c = 0; c < QD; ++c) {
        const float x = x1[(size_t)c * L + l];
        #pragma unroll
        for (int o = 0; o < C; ++o) {
            qa[o] = fmaf(sWq[o * QD + c], x, qa[o]);
            ka[o] = fmaf(sWk[o * QD + c], x, ka[o]);
            va[o] = fmaf(sWv[o * QD + c], x, va[o]);
        }
    }

    const float qs = 0.17677669529663689f;  // 1/sqrt(32)
    float4* qo = (float4*)(qT + (size_t)l * C);
    float4* ko = (float4*)(kT + (size_t)l * C);
    float4* vo = (float4*)(vT + (size_t)l * C);
    #pragma unroll
    for (int i = 0; i < C / 4; ++i) {
        float4 t;
        t.x = (qa[4*i+0] + sb[4*i+0]) * qs;
        t.y = (qa[4*i+1] + sb[4*i+1]) * qs;
        t.z = (qa[4*i+2] + sb[4*i+2]) * qs;
        t.w = (qa[4*i+3] + sb[4*i+3]) * qs;
        qo[i] = t;
        t.x = ka[4*i+0] + sb[C+4*i+0];
        t.y = ka[4*i+1] + sb[C+4*i+1];
        t.z = ka[4*i+2] + sb[C+4*i+2];
        t.w = ka[4*i+3] + sb[C+4*i+3];
        ko[i] = t;
        t.x = va[4*i+0] + sb[2*C+4*i+0];
        t.y = va[4*i+1] + sb[2*C+4*i+1];
        t.z = va[4*i+2] + sb[2*C+4*i+2];
        t.w = va[4*i+3] + sb[2*C+4*i+3];
        vo[i] = t;
    }
}

// ------- kernel 2: fused sliding-window attention + relu + Wo + mask -------
// one thread per query; online softmax over the 1024-key window in
// 128-key LDS chunks. Epilogue: relu -> Wo(64x32) + bo -> *mask -> d_out.
__global__ __launch_bounds__(QT) void att_kernel(
    const float* __restrict__ qT, const float* __restrict__ kT,
    const float* __restrict__ vT, const float* __restrict__ mask,
    const float* __restrict__ Wo, const float* __restrict__ bo,
    float* __restrict__ out, int L)
{
    __shared__ float kS[CK * C];
    __shared__ float vS[CK * C];
    __shared__ float bwS[CK];
    __shared__ float WoS[VD * C];
    __shared__ float boS[VD];

    const int tid  = threadIdx.x;
    const int nblk = blockIdx.x;
    const int qt   = blockIdx.y;
    const int r    = qt * QT + tid;      // row within attention block
    const int gq   = nblk * BLK + r;     // global query position

    for (int i = tid; i < VD * C; i += QT) WoS[i] = Wo[i];
    if (tid < VD) boS[tid] = bo[tid];

    // q fragment (pre-scaled)
    float4 qf[C / 4];
    const float4* qsrc = (const float4*)(qT + (size_t)gq * C);
    #pragma unroll
    for (int i = 0; i < C / 4; ++i) qf[i] = qsrc[i];

    float m = -INFINITY, lsum = 0.f;
    float4 acc4[C / 4];
    #pragma unroll
    for (int i = 0; i < C / 4; ++i) acc4[i] = make_float4(0.f, 0.f, 0.f, 0.f);

    const int myMax = HALF + r;                         // causal bound (cols <= half + row)
    const int maxj  = HALF + qt * QT + (QT - 1);        // max col any thread in wg needs
    const int nch   = min(WW / CK, maxj / CK + 1);

    for (int ch = 0; ch < nch; ++ch) {
        const int jbase = ch * CK;
        const int gk0   = nblk * BLK - HALF + jbase;    // global pos of window col jbase
        __syncthreads();   // protect LDS reuse (also orders WoS staging once)

        float4* kd = (float4*)kS;
        float4* vd = (float4*)vS;
        if (gk0 >= 0 && gk0 + CK <= L) {
            const float4* ks = (const float4*)(kT + (size_t)gk0 * C);
            const float4* vs = (const float4*)(vT + (size_t)gk0 * C);
            for (int i = tid; i < CK * C / 4; i += QT) { kd[i] = ks[i]; vd[i] = vs[i]; }
            bwS[tid] = mask[gk0 + tid];
        } else {
            const float4 z = make_float4(0.f, 0.f, 0.f, 0.f);
            for (int i = tid; i < CK * C / 4; i += QT) {
                const int g = gk0 + (i >> 3);           // 8 float4 per key
                if (g >= 0 && g < L) {
                    kd[i] = ((const float4*)kT)[(size_t)g * 8 + (i & 7)];
                    vd[i] = ((const float4*)vT)[(size_t)g * 8 + (i & 7)];
                } else { kd[i] = z; vd[i] = z; }
            }
            const int g = gk0 + tid;
            bwS[tid] = (g >= 0 && g < L) ? mask[g] : 0.f;
        }
        __syncthreads();

        for (int j = 0; j < CK; j += 4) {
            const int jg = jbase + j;
            if (jg > myMax) break;   // all later cols causally masked (weight ~1e-9: negligible)

            // energies for 4 keys
            float e[4], fm[4];
            #pragma unroll
            for (int u = 0; u < 4; ++u) {
                const float4* kk = (const float4*)(kS + (j + u) * C);
                float s0 = 0.f, s1 = 0.f, s2 = 0.f, s3 = 0.f;
                #pragma unroll
                for (int i = 0; i < C / 4; ++i) {
                    const float4 kv = kk[i];
                    const float4 qv = qf[i];
                    s0 = fmaf(qv.x, kv.x, s0);
                    s1 = fmaf(qv.y, kv.y, s1);
                    s2 = fmaf(qv.z, kv.z, s2);
                    s3 = fmaf(qv.w, kv.w, s3);
                }
                fm[u] = ((jg + u) <= myMax) ? bwS[j + u] : 0.f;
                e[u] = (s0 + s1) + (s2 + s3) + __logf(fm[u] + 1e-9f);
            }

            // online softmax (group of 4)
            float gmax = m;
            #pragma unroll
            for (int u = 0; u < 4; ++u) gmax = fmaxf(gmax, e[u]);
            const float scale = __expf(m - gmax);   // exp(-inf)=0 on first group
            float p[4];
            #pragma unroll
            for (int u = 0; u < 4; ++u) p[u] = __expf(e[u] - gmax);
            lsum = lsum * scale + ((p[0] + p[1]) + (p[2] + p[3]));
            const float w0 = p[0] * fm[0], w1 = p[1] * fm[1];
            const float w2 = p[2] * fm[2], w3 = p[3] * fm[3];
            m = gmax;

            const float4* v0 = (const float4*)(vS + (j + 0) * C);
            const float4* v1 = (const float4*)(vS + (j + 1) * C);
            const float4* v2 = (const float4*)(vS + (j + 2) * C);
            const float4* v3 = (const float4*)(vS + (j + 3) * C);
            #pragma unroll
            for (int i = 0; i < C / 4; ++i) {
                float4 a = acc4[i];
                const float4 b0 = v0[i], b1 = v1[i], b2 = v2[i], b3 = v3[i];
                a.x = fmaf(a.x, scale, 0.f);
                a.y = fmaf(a.y, scale, 0.f);
                a.z = fmaf(a.z, scale, 0.f);
                a.w = fmaf(a.w, scale, 0.f);
                a.x = fmaf(w0, b0.x, a.x); a.x = fmaf(w1, b1.x, a.x);
                a.x = fmaf(w2, b2.x, a.x); a.x = fmaf(w3, b3.x, a.x);
                a.y = fmaf(w0, b0.y, a.y); a.y = fmaf(w1, b1.y, a.y);
                a.y = fmaf(w2, b2.y, a.y); a.y = fmaf(w3, b3.y, a.y);
                a.z = fmaf(w0, b0.z, a.z); a.z = fmaf(w1, b1.z, a.z);
                a.z = fmaf(w2, b2.z, a.z); a.z = fmaf(w3, b3.z, a.z);
                a.w = fmaf(w0, b0.w, a.w); a.w = fmaf(w1, b1.w, a.w);
                a.w = fmaf(w2, b2.w, a.w); a.w = fmaf(w3, b3.w, a.w);
                acc4[i] = a;
            }
        }
    }

    // ---- epilogue: normalize, relu, Wo + bo, * mask ----
    const float inv = 1.0f / lsum;
    float t[C];
    #pragma unroll
    for (int i = 0; i < C / 4; ++i) {
        t[4*i+0] = fmaxf(acc4[i].x * inv, 0.f);
        t[4*i+1] = fmaxf(acc4[i].y * inv, 0.f);
        t[4*i+2] = fmaxf(acc4[i].z * inv, 0.f);
        t[4*i+3] = fmaxf(acc4[i].w * inv, 0.f);
    }
    const float mv = mask[gq];
    #pragma unroll 4
    for (int od = 0; od < VD; ++od) {
        float y0 = 0.f, y1 = 0.f, y2 = 0.f, y3 = 0.f;
        const float* wrow = WoS + od * C;
        #pragma unroll
        for (int o = 0; o < C; o += 4) {
            y0 = fmaf(wrow[o + 0], t[o + 0], y0);
            y1 = fmaf(wrow[o + 1], t[o + 1], y1);
            y2 = fmaf(wrow[o + 2], t[o + 2], y2);
            y3 = fmaf(wrow[o + 3], t[o + 3], y3);
        }
        out[(size_t)od * L + gq] = (((y0 + y1) + (y2 + y3)) + boS[od]) * mv;
    }
}

extern "C" void kernel_launch(void* const* d_in, const int* in_sizes, int n_in,
                              void* d_out, int out_size, void* d_ws, size_t ws_size,
                              hipStream_t stream)
{
    const float* x1   = (const float*)d_in[0];
    // d_in[1] = x2 : unused in encoder stage
    const float* mask = (const float*)d_in[2];
    const float* Wq   = (const float*)d_in[3];
    const float* bq   = (const float*)d_in[4];
    const float* Wk   = (const float*)d_in[5];
    const float* bk   = (const float*)d_in[6];
    const float* Wv   = (const float*)d_in[7];
    const float* bv   = (const float*)d_in[8];
    const float* Wo   = (const float*)d_in[9];
    const float* bo   = (const float*)d_in[10];
    float* out = (float*)d_out;

    const int L = in_sizes[0] / QD;      // 65536
    float* qT = (float*)d_ws;            // L*32 floats
    float* kT = qT + (size_t)L * C;      // L*32 floats
    float* vT = kT + (size_t)L * C;      // L*32 floats

    hipLaunchKernelGGL(qkv_proj, dim3((L + 255) / 256), dim3(256), 0, stream,
                       x1, Wq, bq, Wk, bk, Wv, bv, qT, kT, vT, L);

    const int nb = L / BLK;              // 128
    hipLaunchKernelGGL(att_kernel, dim3(nb, BLK / QT), dim3(QT), 0, stream,
                       qT, kT, vT, mask, Wo, bo, out, L);
}

// Round 2
// 175.118 us; speedup vs baseline: 2.3893x; 2.3893x over previous
//
#include <hip/hip_runtime.h>
#include <math.h>

#define C    32      // attention dim
#define QD   64      // x1 channels
#define VD   64      // output channels
#define BLK  512     // sliding window block length
#define HALF 256

typedef __attribute__((ext_vector_type(8))) short bf16x8;
typedef __attribute__((ext_vector_type(4))) float f32x4;

static __device__ inline unsigned short f2bf(float x) {
    union { float f; unsigned u; } v; v.f = x;
    unsigned r = v.u + 0x7FFFu + ((v.u >> 16) & 1u);   // RNE
    return (unsigned short)(r >> 16);
}

// ---------------- kernel 1: QKV projection (scalar-load weights) ----------
// kind 0 -> qT bf16 (L,32) pre-scaled by 1/sqrt(32)
// kind 1 -> kT bf16 (L,32)
// kind 2 -> vTc bf16 channel-major (32,L)
__global__ __launch_bounds__(256) void qkv_proj(
    const float* __restrict__ x1,
    const float* __restrict__ Wq, const float* __restrict__ bq,
    const float* __restrict__ Wk, const float* __restrict__ bk,
    const float* __restrict__ Wv, const float* __restrict__ bv,
    unsigned short* __restrict__ qT, unsigned short* __restrict__ kT,
    unsigned short* __restrict__ vTc, int L)
{
    const int kind = blockIdx.y;
    const float* __restrict__ W = (kind == 0) ? Wq : ((kind == 1) ? Wk : Wv);
    const float* __restrict__ b = (kind == 0) ? bq : ((kind == 1) ? bk : bv);

    const int l = blockIdx.x * 256 + threadIdx.x;

    float acc[C];
    #pragma unroll
    for (int o = 0; o < C; ++o) acc[o] = 0.f;

    #pragma unroll 4
    for (int c = 0; c < QD; ++c) {
        const float x = x1[(size_t)c * L + l];       // coalesced
        #pragma unroll
        for (int o = 0; o < C; ++o)
            acc[o] = fmaf(W[o * QD + c], x, acc[o]); // W: uniform -> s_load
    }

    if (kind == 2) {
        #pragma unroll
        for (int o = 0; o < C; ++o)
            vTc[(size_t)o * L + l] = f2bf(acc[o] + b[o]);
    } else {
        const float s = (kind == 0) ? 0.17677669529663689f : 1.0f;
        unsigned short h[C];
        #pragma unroll
        for (int o = 0; o < C; ++o) h[o] = f2bf((acc[o] + b[o]) * s);
        unsigned short* base = ((kind == 0) ? qT : kT) + (size_t)l * C;
        uint4* dst = (uint4*)base;
        const uint4* src = (const uint4*)h;
        #pragma unroll
        for (int i = 0; i < 4; ++i) dst[i] = src[i];
    }
}

// ---------------- kernel 2: MFMA flash attention + fused epilogue ---------
// 1 wave (64 thr) per 16 queries. Window per query gq in block nblk:
// keys in [max(0, nblk*512-256), gq]  (derived from reference's col<=half+row).
__global__ __launch_bounds__(64, 4) void att_kernel(
    const unsigned short* __restrict__ qT,
    const unsigned short* __restrict__ kT,
    const unsigned short* __restrict__ vTc,
    const float* __restrict__ mask,
    const float* __restrict__ Wo, const float* __restrict__ bo,
    float* __restrict__ out, int L)
{
    __shared__ float pS[16 * 36];   // 16 rows, stride 36 (16B-aligned rows, conflict-light)

    const int lane = threadIdx.x;
    const int lo   = lane & 15;
    const int quad = lane >> 4;

    const int wq0    = blockIdx.x * 16;           // first query of this wave
    const int nblk   = wq0 >> 9;                  // 512-block id
    const int kstart = max(0, (nblk << 9) - HALF);
    const int qmax   = wq0 + 15;

    // Q A-frag: A[m=lo][k=quad*8+j], row-major (L,32) bf16, pre-scaled
    const bf16x8 qA = *(const bf16x8*)(qT + (size_t)(wq0 + lo) * C + quad * 8);

    // Wo B-frags (4 od-tiles): B[k=c][n=od_local], lane n=lo reads Wo[od][c]
    bf16x8 woB[4];
    #pragma unroll
    for (int t = 0; t < 4; ++t) {
        #pragma unroll
        for (int j = 0; j < 8; ++j)
            woB[t][j] = (short)f2bf(Wo[(size_t)(t * 16 + lo) * C + quad * 8 + j]);
    }

    const f32x4 zero = {0.f, 0.f, 0.f, 0.f};
    f32x4 O0 = zero, O1 = zero;                    // O C-frags: ch 0-15 / 16-31
    float Mrow[4] = {-INFINITY, -INFINITY, -INFINITY, -INFINITY};
    float lrow[4] = {0.f, 0.f, 0.f, 0.f};

    for (int kb = kstart; kb <= qmax; kb += 32) {
        const bool t1 = (kb + 16 <= qmax);

        // K B-frags: B[k=ch][n=key], lane n=lo reads key's 8 contiguous channels
        const bf16x8 kB0 = *(const bf16x8*)(kT + (size_t)(kb + lo) * C + quad * 8);
        // V B-frags: B[k=key][n=ch], channel-major vTc rows
        const bf16x8 vB0 = *(const bf16x8*)(vTc + (size_t)lo * L + kb + quad * 8);
        const bf16x8 vB1 = *(const bf16x8*)(vTc + (size_t)(lo + 16) * L + kb + quad * 8);
        const float fm0 = mask[kb + lo];
        float fm1 = 1.f;
        bf16x8 kB1 = kB0;
        if (t1) {
            kB1 = *(const bf16x8*)(kT + (size_t)(kb + 16 + lo) * C + quad * 8);
            fm1 = mask[kb + 16 + lo];
        }

        f32x4 S0 = __builtin_amdgcn_mfma_f32_16x16x32_bf16(qA, kB0, zero, 0, 0, 0);
        f32x4 S1 = zero;
        if (t1) S1 = __builtin_amdgcn_mfma_f32_16x16x32_bf16(qA, kB1, zero, 0, 0, 0);

        const float lg0 = __logf(fm0 + 1e-9f);
        const float lg1 = __logf(fm1 + 1e-9f);
        const int key0 = kb + lo, key1 = kb + 16 + lo;

        float e0[4], e1[4], p0[4], p1[4], alpha[4];
        #pragma unroll
        for (int r = 0; r < 4; ++r) {
            const int q = wq0 + quad * 4 + r;      // this lane's C-frag row
            e0[r] = (key0 <= q) ? (S0[r] + lg0) : -INFINITY;
            e1[r] = (key1 <= q) ? (S1[r] + lg1) : -INFINITY;
            float rm = fmaxf(e0[r], e1[r]);
            rm = fmaxf(rm, __shfl_xor(rm, 1));
            rm = fmaxf(rm, __shfl_xor(rm, 2));
            rm = fmaxf(rm, __shfl_xor(rm, 4));
            rm = fmaxf(rm, __shfl_xor(rm, 8));
            const float Mnew = fmaxf(Mrow[r], rm);
            alpha[r] = __expf(Mrow[r] - Mnew);     // first chunk: exp(-inf)=0
            Mrow[r] = Mnew;
            p0[r] = __expf(e0[r] - Mnew);
            p1[r] = __expf(e1[r] - Mnew);
            float rs = p0[r] + p1[r];
            rs += __shfl_xor(rs, 1);
            rs += __shfl_xor(rs, 2);
            rs += __shfl_xor(rs, 4);
            rs += __shfl_xor(rs, 8);
            lrow[r] = lrow[r] * alpha[r] + rs;
        }

        // P (= p * fmask) -> LDS in C-layout
        #pragma unroll
        for (int r = 0; r < 4; ++r) {
            pS[(quad * 4 + r) * 36 + lo]      = p0[r] * fm0;
            pS[(quad * 4 + r) * 36 + 16 + lo] = p1[r] * fm1;
        }
        __syncthreads();
        // read back in A-layout: A[m=lo][k=quad*8+j]
        float pA[8];
        *(f32x4*)pA       = *(const f32x4*)&pS[lo * 36 + quad * 8];
        *(f32x4*)(pA + 4) = *(const f32x4*)&pS[lo * 36 + quad * 8 + 4];
        __syncthreads();
        bf16x8 pF;
        #pragma unroll
        for (int j = 0; j < 8; ++j) pF[j] = (short)f2bf(pA[j]);

        // rescale accumulators, then PV
        #pragma unroll
        for (int r = 0; r < 4; ++r) { O0[r] *= alpha[r]; O1[r] *= alpha[r]; }
        O0 = __builtin_amdgcn_mfma_f32_16x16x32_bf16(pF, vB0, O0, 0, 0, 0);
        O1 = __builtin_amdgcn_mfma_f32_16x16x32_bf16(pF, vB1, O1, 0, 0, 0);
    }

    // ---- epilogue: normalize, relu, T->LDS, Wo MFMA, +bo, *mask, store ----
    float inv[4];
    #pragma unroll
    for (int r = 0; r < 4; ++r) inv[r] = 1.f / lrow[r];

    #pragma unroll
    for (int r = 0; r < 4; ++r) {
        pS[(quad * 4 + r) * 36 + lo]      = fmaxf(O0[r] * inv[r], 0.f);
        pS[(quad * 4 + r) * 36 + 16 + lo] = fmaxf(O1[r] * inv[r], 0.f);
    }
    __syncthreads();
    float tA[8];
    *(f32x4*)tA       = *(const f32x4*)&pS[lo * 36 + quad * 8];
    *(f32x4*)(tA + 4) = *(const f32x4*)&pS[lo * 36 + quad * 8 + 4];
    bf16x8 tF;
    #pragma unroll
    for (int j = 0; j < 8; ++j) tF[j] = (short)f2bf(tA[j]);

    float mk[4];
    #pragma unroll
    for (int r = 0; r < 4; ++r) mk[r] = mask[wq0 + quad * 4 + r];

    #pragma unroll
    for (int t = 0; t < 4; ++t) {
        const f32x4 R = __builtin_amdgcn_mfma_f32_16x16x32_bf16(tF, woB[t], zero, 0, 0, 0);
        const int od = t * 16 + lo;
        const float bov = bo[od];
        #pragma unroll
        for (int r = 0; r < 4; ++r)
            out[(size_t)od * L + wq0 + quad * 4 + r] = (R[r] + bov) * mk[r];
    }
}

extern "C" void kernel_launch(void* const* d_in, const int* in_sizes, int n_in,
                              void* d_out, int out_size, void* d_ws, size_t ws_size,
                              hipStream_t stream)
{
    const float* x1   = (const float*)d_in[0];
    // d_in[1] = x2 : unused (encoder stage)
    const float* mask = (const float*)d_in[2];
    const float* Wq   = (const float*)d_in[3];
    const float* bq   = (const float*)d_in[4];
    const float* Wk   = (const float*)d_in[5];
    const float* bk   = (const float*)d_in[6];
    const float* Wv   = (const float*)d_in[7];
    const float* bv   = (const float*)d_in[8];
    const float* Wo   = (const float*)d_in[9];
    const float* bo   = (const float*)d_in[10];
    float* out = (float*)d_out;

    const int L = in_sizes[0] / QD;                  // 65536
    unsigned short* qT  = (unsigned short*)d_ws;     // L*32 bf16
    unsigned short* kT  = qT + (size_t)L * C;        // L*32 bf16
    unsigned short* vTc = kT + (size_t)L * C;        // 32*L bf16 (channel-major)

    hipLaunchKernelGGL(qkv_proj, dim3(L / 256, 3), dim3(256), 0, stream,
                       x1, Wq, bq, Wk, bk, Wv, bv, qT, kT, vTc, L);

    hipLaunchKernelGGL(att_kernel, dim3(L / 16), dim3(64), 0, stream,
                       qT, kT, vTc, mask, Wo, bo, out, L);
}

// Round 3
// 165.784 us; speedup vs baseline: 2.5239x; 1.0563x over previous
//
#include <hip/hip_runtime.h>
#include <hip/hip_bf16.h>
#include <math.h>

#define C    32      // attention dim
#define QD   64      // x1 channels
#define VD   64      // output channels
#define BLK  512     // sliding window block length
#define HALF 256

typedef __attribute__((ext_vector_type(8))) short bf16x8;
typedef __attribute__((ext_vector_type(4))) float f32x4;

static __device__ inline unsigned short f2bf(float x) {
    union { float f; unsigned u; } v; v.f = x;
    unsigned r = v.u + 0x7FFFu + ((v.u >> 16) & 1u);   // RNE
    return (unsigned short)(r >> 16);
}

// pack 8 floats -> bf16x8 (lets hip header pick v_cvt_pk_bf16_f32 if present)
static __device__ inline bf16x8 pack8(const float* v) {
    union { __hip_bfloat162 h2[4]; bf16x8 vec; } u;
    #pragma unroll
    for (int i = 0; i < 4; ++i)
        u.h2[i] = __float22bfloat162_rn(make_float2(v[2 * i], v[2 * i + 1]));
    return u.vec;
}

// ---------------- kernel 1: QKV projection ----------------
// kind 0 -> qT bf16 (L,32) pre-scaled by 1/sqrt(32)
// kind 1 -> kT bf16 (L,32)
// kind 2 -> vTc bf16 channel-major (32,L)
__global__ __launch_bounds__(256) void qkv_proj(
    const float* __restrict__ x1,
    const float* __restrict__ Wq, const float* __restrict__ bq,
    const float* __restrict__ Wk, const float* __restrict__ bk,
    const float* __restrict__ Wv, const float* __restrict__ bv,
    unsigned short* __restrict__ qT, unsigned short* __restrict__ kT,
    unsigned short* __restrict__ vTc, int L)
{
    const int kind = blockIdx.y;
    const float* __restrict__ W = (kind == 0) ? Wq : ((kind == 1) ? Wk : Wv);
    const float* __restrict__ b = (kind == 0) ? bq : ((kind == 1) ? bk : bv);

    const int l = blockIdx.x * 256 + threadIdx.x;

    // hoist all 64 input loads (64 outstanding vmem, then pure VALU)
    float x[QD];
    #pragma unroll
    for (int c = 0; c < QD; ++c) x[c] = x1[(size_t)c * L + l];

    float acc[C];
    #pragma unroll
    for (int o = 0; o < C; ++o) acc[o] = 0.f;

    #pragma unroll
    for (int c = 0; c < QD; ++c) {
        #pragma unroll
        for (int o = 0; o < C; ++o)
            acc[o] = fmaf(W[o * QD + c], x[c], acc[o]);   // W uniform -> s_load
    }

    if (kind == 2) {
        #pragma unroll
        for (int o = 0; o < C; ++o)
            vTc[(size_t)o * L + l] = f2bf(acc[o] + b[o]);
    } else {
        const float s = (kind == 0) ? 0.17677669529663689f : 1.0f;
        unsigned short h[C];
        #pragma unroll
        for (int o = 0; o < C; ++o) h[o] = f2bf((acc[o] + b[o]) * s);
        unsigned short* base = ((kind == 0) ? qT : kT) + (size_t)l * C;
        uint4* dst = (uint4*)base;
        const uint4* src = (const uint4*)h;
        #pragma unroll
        for (int i = 0; i < 4; ++i) dst[i] = src[i];
    }
}

// ---------------- kernel 2: MFMA flash attention, deferred-sum softmax ----
// 1 wave per 16 queries; 64-key chunks; no in-loop cross-lane ops.
#define PSTR 68                       // f32 LDS row stride (64 + 4 pad)
__global__ __launch_bounds__(64, 4) void att_kernel(
    const unsigned short* __restrict__ qT,
    const unsigned short* __restrict__ kT,
    const unsigned short* __restrict__ vTc,
    const float* __restrict__ mask,
    const float* __restrict__ Wo, const float* __restrict__ bo,
    float* __restrict__ out, int L)
{
    __shared__ float pS[2 * 16 * PSTR];   // double-buffered P chunk (2 x 4352 B)

    const int lane = threadIdx.x;
    const int lo   = lane & 15;
    const int quad = lane >> 4;

    // XCD swizzle: all 32 waves of one 512-window share (blockIdx % 8) == w % 8
    const int id  = blockIdx.x;
    const int w   = (id & 7) + 8 * ((id >> 3) >> 5);   // window 0..nb-1
    const int s   = (id >> 3) & 31;                    // wave within window
    const int wq0 = w * BLK + s * 16;

    const int kstart = max(0, w * BLK - HALF);
    const int qmax   = wq0 + 15;

    // Q A-frag: A[m=lo][k=quad*8+j]
    const bf16x8 qA = *(const bf16x8*)(qT + (size_t)(wq0 + lo) * C + quad * 8);

    const f32x4 zero = {0.f, 0.f, 0.f, 0.f};
    f32x4 O0 = zero, O1 = zero;
    float ps[4] = {0.f, 0.f, 0.f, 0.f};   // per-lane partial denominators

    int buf = 0;
    for (int kb = kstart; kb <= qmax; kb += 64, buf ^= 1) {
        float* pb = pS + buf * (16 * PSTR);

        bf16x8 kB[4];
        float fm[4];
        #pragma unroll
        for (int t = 0; t < 4; ++t) {
            kB[t] = *(const bf16x8*)(kT + (size_t)(kb + t * 16 + lo) * C + quad * 8);
            fm[t] = mask[min(kb + t * 16 + lo, L - 1)];
        }
        bf16x8 vB[2][2];
        #pragma unroll
        for (int h = 0; h < 2; ++h)
            #pragma unroll
            for (int c2 = 0; c2 < 2; ++c2)
                vB[h][c2] = *(const bf16x8*)(vTc + (size_t)(c2 * 16 + lo) * L + kb + h * 32 + quad * 8);

        f32x4 S[4];
        #pragma unroll
        for (int t = 0; t < 4; ++t)
            S[t] = __builtin_amdgcn_mfma_f32_16x16x32_bf16(qA, kB[t], zero, 0, 0, 0);

        // p = exp(S) * (fm+1e-9) * [key <= q]; accumulate denominator partials
        #pragma unroll
        for (int t = 0; t < 4; ++t) {
            const int key  = kb + t * 16 + lo;
            const float af = fm[t] + 1e-9f;
            #pragma unroll
            for (int r = 0; r < 4; ++r) {
                const float wgt = (key <= wq0 + quad * 4 + r) ? af : 0.f;
                const float pd  = __expf(S[t][r]) * wgt;
                ps[r] += pd;
                pb[(quad * 4 + r) * PSTR + t * 16 + lo] = pd * fm[t];
            }
        }
        __syncthreads();

        // read P back in A-layout, pack to bf16
        float pA[16];
        *(f32x4*)(pA + 0)  = *(const f32x4*)&pb[lo * PSTR + quad * 8];
        *(f32x4*)(pA + 4)  = *(const f32x4*)&pb[lo * PSTR + quad * 8 + 4];
        *(f32x4*)(pA + 8)  = *(const f32x4*)&pb[lo * PSTR + 32 + quad * 8];
        *(f32x4*)(pA + 12) = *(const f32x4*)&pb[lo * PSTR + 32 + quad * 8 + 4];
        const bf16x8 pF0 = pack8(pA);
        const bf16x8 pF1 = pack8(pA + 8);

        O0 = __builtin_amdgcn_mfma_f32_16x16x32_bf16(pF0, vB[0][0], O0, 0, 0, 0);
        O0 = __builtin_amdgcn_mfma_f32_16x16x32_bf16(pF1, vB[1][0], O0, 0, 0, 0);
        O1 = __builtin_amdgcn_mfma_f32_16x16x32_bf16(pF0, vB[0][1], O1, 0, 0, 0);
        O1 = __builtin_amdgcn_mfma_f32_16x16x32_bf16(pF1, vB[1][1], O1, 0, 0, 0);
    }

    // ---- deferred denominator reduction (only cross-lane ops in kernel) ----
    #pragma unroll
    for (int r = 0; r < 4; ++r) {
        float t = ps[r];
        t += __shfl_xor(t, 1);
        t += __shfl_xor(t, 2);
        t += __shfl_xor(t, 4);
        t += __shfl_xor(t, 8);
        ps[r] = 1.f / t;
    }

    // ---- epilogue: normalize, relu, transpose via LDS, Wo MFMA, store ----
    __syncthreads();
    #pragma unroll
    for (int r = 0; r < 4; ++r) {
        pS[(quad * 4 + r) * PSTR + lo]      = fmaxf(O0[r] * ps[r], 0.f);
        pS[(quad * 4 + r) * PSTR + 16 + lo] = fmaxf(O1[r] * ps[r], 0.f);
    }
    __syncthreads();
    float tA[8];
    *(f32x4*)tA       = *(const f32x4*)&pS[lo * PSTR + quad * 8];
    *(f32x4*)(tA + 4) = *(const f32x4*)&pS[lo * PSTR + quad * 8 + 4];
    const bf16x8 tF = pack8(tA);

    float mk[4];
    #pragma unroll
    for (int r = 0; r < 4; ++r) mk[r] = mask[wq0 + quad * 4 + r];

    #pragma unroll
    for (int t = 0; t < 4; ++t) {
        float wtmp[8];
        *(float4*)wtmp       = *(const float4*)(Wo + (size_t)(t * 16 + lo) * C + quad * 8);
        *(float4*)(wtmp + 4) = *(const float4*)(Wo + (size_t)(t * 16 + lo) * C + quad * 8 + 4);
        const bf16x8 woB = pack8(wtmp);
        const f32x4 R = __builtin_amdgcn_mfma_f32_16x16x32_bf16(tF, woB, zero, 0, 0, 0);
        const int od = t * 16 + lo;
        const float bov = bo[od];
        #pragma unroll
        for (int r = 0; r < 4; ++r)
            out[(size_t)od * L + wq0 + quad * 4 + r] = (R[r] + bov) * mk[r];
    }
}

extern "C" void kernel_launch(void* const* d_in, const int* in_sizes, int n_in,
                              void* d_out, int out_size, void* d_ws, size_t ws_size,
                              hipStream_t stream)
{
    const float* x1   = (const float*)d_in[0];
    // d_in[1] = x2 : unused (encoder stage)
    const float* mask = (const float*)d_in[2];
    const float* Wq   = (const float*)d_in[3];
    const float* bq   = (const float*)d_in[4];
    const float* Wk   = (const float*)d_in[5];
    const float* bk   = (const float*)d_in[6];
    const float* Wv   = (const float*)d_in[7];
    const float* bv   = (const float*)d_in[8];
    const float* Wo   = (const float*)d_in[9];
    const float* bo   = (const float*)d_in[10];
    float* out = (float*)d_out;

    const int L = in_sizes[0] / QD;                  // 65536
    unsigned short* qT  = (unsigned short*)d_ws;     // L*32 bf16
    unsigned short* kT  = qT + (size_t)L * C;        // L*32 bf16
    unsigned short* vTc = kT + (size_t)L * C;        // 32*L bf16 (+ OOB slack after)

    hipLaunchKernelGGL(qkv_proj, dim3(L / 256, 3), dim3(256), 0, stream,
                       x1, Wq, bq, Wk, bk, Wv, bv, qT, kT, vTc, L);

    hipLaunchKernelGGL(att_kernel, dim3(L / 16), dim3(64), 0, stream,
                       qT, kT, vTc, mask, Wo, bo, out, L);
}

// Round 4
// 163.216 us; speedup vs baseline: 2.5636x; 1.0157x over previous
//
#include <hip/hip_runtime.h>
#include <hip/hip_bf16.h>
#include <math.h>

#define C    32      // attention dim
#define QD   64      // x1 channels
#define VD   64      // output channels
#define BLK  512     // sliding window block length
#define HALF 256

typedef __attribute__((ext_vector_type(8))) short bf16x8;
typedef __attribute__((ext_vector_type(4))) float f32x4;

static __device__ inline unsigned short f2bf(float x) {
    union { float f; unsigned u; } v; v.f = x;
    unsigned r = v.u + 0x7FFFu + ((v.u >> 16) & 1u);   // RNE
    return (unsigned short)(r >> 16);
}

// pack 2 floats -> one dword holding 2 bf16 (low = a, high = b)
static __device__ inline unsigned pk2(float a, float b) {
    union { __hip_bfloat162 h; unsigned u; } x;
    x.h = __float22bfloat162_rn(make_float2(a, b));
    return x.u;
}

// ---------------- kernel 1: QKV projection (R2 variant) ----------------
// kind 0 -> qT bf16 (L,32) pre-scaled by 1/sqrt(32)
// kind 1 -> kT bf16 (L,32)
// kind 2 -> vTc bf16 channel-major (32,L)
__global__ __launch_bounds__(256) void qkv_proj(
    const float* __restrict__ x1,
    const float* __restrict__ Wq, const float* __restrict__ bq,
    const float* __restrict__ Wk, const float* __restrict__ bk,
    const float* __restrict__ Wv, const float* __restrict__ bv,
    unsigned short* __restrict__ qT, unsigned short* __restrict__ kT,
    unsigned short* __restrict__ vTc, int L)
{
    const int kind = blockIdx.y;
    const float* __restrict__ W = (kind == 0) ? Wq : ((kind == 1) ? Wk : Wv);
    const float* __restrict__ b = (kind == 0) ? bq : ((kind == 1) ? bk : bv);

    const int l = blockIdx.x * 256 + threadIdx.x;

    float acc[C];
    #pragma unroll
    for (int o = 0; o < C; ++o) acc[o] = 0.f;

    #pragma unroll 4
    for (int c = 0; c < QD; ++c) {
        const float x = x1[(size_t)c * L + l];       // coalesced
        #pragma unroll
        for (int o = 0; o < C; ++o)
            acc[o] = fmaf(W[o * QD + c], x, acc[o]); // W uniform -> s_load
    }

    if (kind == 2) {
        #pragma unroll
        for (int o = 0; o < C; ++o)
            vTc[(size_t)o * L + l] = f2bf(acc[o] + b[o]);
    } else {
        const float s = (kind == 0) ? 0.17677669529663689f : 1.0f;
        unsigned short h[C];
        #pragma unroll
        for (int o = 0; o < C; ++o) h[o] = f2bf((acc[o] + b[o]) * s);
        unsigned short* base = ((kind == 0) ? qT : kT) + (size_t)l * C;
        uint4* dst = (uint4*)base;
        const uint4* src = (const uint4*)h;
        #pragma unroll
        for (int i = 0; i < 4; ++i) dst[i] = src[i];
    }
}

// ---------------- kernel 2: MFMA flash attention, S^T form ----------------
// 4 independent waves per 256-thr wg, 16 queries per wave, 64-key chunks.
// No LDS, no barriers: P^T C-layout -> B-layout via quad-permute shuffles.
__global__ __launch_bounds__(256, 4) void att_kernel(
    const unsigned short* __restrict__ qT,
    const unsigned short* __restrict__ kT,
    const unsigned short* __restrict__ vTc,
    const float* __restrict__ mask,
    const float* __restrict__ Wo, const float* __restrict__ bo,
    float* __restrict__ out, int L)
{
    const int tid  = threadIdx.x;
    const int lane = tid & 63;
    const int widx = tid >> 6;
    const int lo   = lane & 15;
    const int quad = lane >> 4;

    // XCD swizzle: 8 wgs per 512-window, id%8 spreads windows across XCDs
    const int id  = blockIdx.x;
    const int w   = (id & 7) + 8 * (id >> 6);     // window 0..127
    const int oct = (id >> 3) & 7;                // wg octant within window
    const int s   = oct * 4 + widx;               // wave slot 0..31
    const int wq0 = w * BLK + s * 16;

    const int kstart = max(0, w * BLK - HALF);
    const int qmax   = wq0 + 15;
    const int myq    = wq0 + lo;                  // this lane's query (col in S^T)

    // Q B-frag: B[k=c][n=q], lane n=lo reads 8 consecutive channels of its query
    const bf16x8 qB = *(const bf16x8*)(qT + (size_t)myq * C + quad * 8);

    const f32x4 zero = {0.f, 0.f, 0.f, 0.f};
    f32x4 O0 = zero, O1 = zero;                   // O^T C-frags: ch 0-15 / 16-31
    float psum = 0.f;                             // per-lane denominator partial (query=lo)

    for (int kb = kstart; kb <= qmax; kb += 64) {
        // S^T tiles: A=K (m=key), B=Q (n=query); C-layout: col=q=lo, row=key=quad*4+r
        f32x4 S[4];
        float4 fm4[4];
        #pragma unroll
        for (int t = 0; t < 4; ++t) {
            const int krow = kb + t * 16 + lo;
            const bf16x8 kA = *(const bf16x8*)(kT + (size_t)min(krow, L - 1) * C + quad * 8);
            S[t] = __builtin_amdgcn_mfma_f32_16x16x32_bf16(kA, qB, zero, 0, 0, 0);
            fm4[t] = *(const float4*)(mask + min(kb + t * 16 + quad * 4, L - 4));
        }

        // p = exp(S)*(fm+1e-9)*[key<=q]; P = p*fm, packed to bf16 pairs along r
        unsigned wp[4][2];
        #pragma unroll
        for (int t = 0; t < 4; ++t) {
            const float* fmp = (const float*)&fm4[t];
            float p[4];
            #pragma unroll
            for (int r = 0; r < 4; ++r) {
                const int key = kb + t * 16 + quad * 4 + r;
                const float pd = (key <= myq) ? __expf(S[t][r]) * (fmp[r] + 1e-9f) : 0.f;
                psum += pd;
                p[r] = pd * fmp[r];
            }
            wp[t][0] = pk2(p[0], p[1]);
            wp[t][1] = pk2(p[2], p[3]);
        }

        // quad-permute C-layout -> B-layout; PV: O^T += V^T * P^T
        const int qsl = lo + 16 * ((quad & 1) << 1);
        #pragma unroll
        for (int g = 0; g < 2; ++g) {
            union { int i[4]; bf16x8 v; } pb;
            #pragma unroll
            for (int i = 0; i < 4; ++i) {
                const int src = qsl + 16 * (i >> 1);
                const int v0 = __shfl((int)wp[2 * g][i & 1], src);
                const int v1 = __shfl((int)wp[2 * g + 1][i & 1], src);
                pb.i[i] = (quad < 2) ? v0 : v1;
            }
            const int vb = min(kb + g * 32 + quad * 8, L - 8);
            const bf16x8 vA0 = *(const bf16x8*)(vTc + (size_t)lo * L + vb);
            const bf16x8 vA1 = *(const bf16x8*)(vTc + (size_t)(lo + 16) * L + vb);
            O0 = __builtin_amdgcn_mfma_f32_16x16x32_bf16(vA0, pb.v, O0, 0, 0, 0);
            O1 = __builtin_amdgcn_mfma_f32_16x16x32_bf16(vA1, pb.v, O1, 0, 0, 0);
        }
    }

    // ---- denominator: sum the 4 quads' partials for each query col ----
    float dsum = psum;
    dsum += __shfl_xor(dsum, 16);
    dsum += __shfl_xor(dsum, 32);
    const float inv = 1.f / dsum;

    // ---- epilogue: T = relu(O^T*inv) -> B-layout via same quad-permute ----
    unsigned tw[2][2];
    tw[0][0] = pk2(fmaxf(O0[0] * inv, 0.f), fmaxf(O0[1] * inv, 0.f));
    tw[0][1] = pk2(fmaxf(O0[2] * inv, 0.f), fmaxf(O0[3] * inv, 0.f));
    tw[1][0] = pk2(fmaxf(O1[0] * inv, 0.f), fmaxf(O1[1] * inv, 0.f));
    tw[1][1] = pk2(fmaxf(O1[2] * inv, 0.f), fmaxf(O1[3] * inv, 0.f));

    union { int i[4]; bf16x8 v; } tb;
    {
        const int qsl = lo + 16 * ((quad & 1) << 1);
        #pragma unroll
        for (int i = 0; i < 4; ++i) {
            const int src = qsl + 16 * (i >> 1);
            const int v0 = __shfl((int)tw[0][i & 1], src);
            const int v1 = __shfl((int)tw[1][i & 1], src);
            tb.i[i] = (quad < 2) ? v0 : v1;
        }
    }

    const float mk = mask[myq];
    #pragma unroll
    for (int t = 0; t < 4; ++t) {
        float wtmp[8];
        *(float4*)&wtmp[0] = *(const float4*)(Wo + (size_t)(t * 16 + lo) * C + quad * 8);
        *(float4*)&wtmp[4] = *(const float4*)(Wo + (size_t)(t * 16 + lo) * C + quad * 8 + 4);
        union { unsigned u[4]; bf16x8 v; } wo;
        #pragma unroll
        for (int i = 0; i < 4; ++i) wo.u[i] = pk2(wtmp[2 * i], wtmp[2 * i + 1]);
        const f32x4 R = __builtin_amdgcn_mfma_f32_16x16x32_bf16(wo.v, tb.v, zero, 0, 0, 0);
        const float4 bo4 = *(const float4*)(bo + t * 16 + quad * 4);
        const float* bop = (const float*)&bo4;
        #pragma unroll
        for (int r = 0; r < 4; ++r)
            out[(size_t)(t * 16 + quad * 4 + r) * L + myq] = (R[r] + bop[r]) * mk;
    }
}

extern "C" void kernel_launch(void* const* d_in, const int* in_sizes, int n_in,
                              void* d_out, int out_size, void* d_ws, size_t ws_size,
                              hipStream_t stream)
{
    const float* x1   = (const float*)d_in[0];
    // d_in[1] = x2 : unused (encoder stage)
    const float* mask = (const float*)d_in[2];
    const float* Wq   = (const float*)d_in[3];
    const float* bq   = (const float*)d_in[4];
    const float* Wk   = (const float*)d_in[5];
    const float* bk   = (const float*)d_in[6];
    const float* Wv   = (const float*)d_in[7];
    const float* bv   = (const float*)d_in[8];
    const float* Wo   = (const float*)d_in[9];
    const float* bo   = (const float*)d_in[10];
    float* out = (float*)d_out;

    const int L = in_sizes[0] / QD;                  // 65536
    unsigned short* qT  = (unsigned short*)d_ws;     // L*32 bf16
    unsigned short* kT  = qT + (size_t)L * C;        // L*32 bf16
    unsigned short* vTc = kT + (size_t)L * C;        // 32*L bf16 (channel-major)

    hipLaunchKernelGGL(qkv_proj, dim3(L / 256, 3), dim3(256), 0, stream,
                       x1, Wq, bq, Wk, bk, Wv, bv, qT, kT, vTc, L);

    hipLaunchKernelGGL(att_kernel, dim3((L / BLK) * 8), dim3(256), 0, stream,
                       qT, kT, vTc, mask, Wo, bo, out, L);
}

// Round 6
// 146.652 us; speedup vs baseline: 2.8531x; 1.1129x over previous
//
#include <hip/hip_runtime.h>
#include <hip/hip_bf16.h>
#include <math.h>

#define C    32      // attention dim
#define QD   64      // x1 channels
#define VD   64      // output channels
#define BLK  512     // sliding window block length
#define HALF 256

typedef __attribute__((ext_vector_type(8))) short bf16x8;
typedef __attribute__((ext_vector_type(4))) float f32x4;

static __device__ inline unsigned short f2bf(float x) {
    union { float f; unsigned u; } v; v.f = x;
    unsigned r = v.u + 0x7FFFu + ((v.u >> 16) & 1u);   // RNE
    return (unsigned short)(r >> 16);
}

// pack 2 floats -> one dword holding 2 bf16 (low = a, high = b)
static __device__ inline unsigned pk2(float a, float b) {
    union { __hip_bfloat162 h; unsigned u; } x;
    x.h = __float22bfloat162_rn(make_float2(a, b));
    return x.u;
}

// ---------------- kernel 1: QKV projection ----------------
// kind 0 -> qT bf16 (L,32) pre-scaled by 1/sqrt(32)
// kind 1 -> kT bf16 (L,32)
// kind 2 -> v2 bf16 tiled: [l>>6][(l>>5)&1][ch][l&31]  (2048 elems / 64-key block)
__global__ __launch_bounds__(256) void qkv_proj(
    const float* __restrict__ x1,
    const float* __restrict__ Wq, const float* __restrict__ bq,
    const float* __restrict__ Wk, const float* __restrict__ bk,
    const float* __restrict__ Wv, const float* __restrict__ bv,
    unsigned short* __restrict__ qT, unsigned short* __restrict__ kT,
    unsigned short* __restrict__ v2, int L)
{
    const int kind = blockIdx.y;
    const float* __restrict__ W = (kind == 0) ? Wq : ((kind == 1) ? Wk : Wv);
    const float* __restrict__ b = (kind == 0) ? bq : ((kind == 1) ? bk : bv);

    const int l = blockIdx.x * 256 + threadIdx.x;

    float acc[C];
    #pragma unroll
    for (int o = 0; o < C; ++o) acc[o] = 0.f;

    #pragma unroll 4
    for (int c = 0; c < QD; ++c) {
        const float x = x1[(size_t)c * L + l];       // coalesced
        #pragma unroll
        for (int o = 0; o < C; ++o)
            acc[o] = fmaf(W[o * QD + c], x, acc[o]); // W uniform -> s_load
    }

    if (kind == 2) {
        unsigned short* dst = v2 + ((size_t)(l >> 6) << 11) + (((l >> 5) & 1) << 10) + (l & 31);
        #pragma unroll
        for (int o = 0; o < C; ++o)
            dst[o << 5] = f2bf(acc[o] + b[o]);
    } else {
        const float s = (kind == 0) ? 0.17677669529663689f : 1.0f;
        unsigned short h[C];
        #pragma unroll
        for (int o = 0; o < C; ++o) h[o] = f2bf((acc[o] + b[o]) * s);
        unsigned short* base = ((kind == 0) ? qT : kT) + (size_t)l * C;
        uint4* dst = (uint4*)base;
        const uint4* src = (const uint4*)h;
        #pragma unroll
        for (int i = 0; i < 4; ++i) dst[i] = src[i];
    }
}

// ---------------- kernel 2: MFMA flash attention, split-K waves ----------
// wg = 128 thr = 2 waves covering the SAME 16 queries, alternate 64-key
// chunks (deferred-sum softmax is order-independent). LPT dispatch order,
// XCD-affine. Exactly one causal chunk per tile; full chunks have no
// compares and no clamps (index ranges proven in-bounds).
// Grid MUST be L/16 wgs (one per 16-query tile) — R5 launched half and failed.
__global__ __launch_bounds__(128, 8) void att_kernel(
    const unsigned short* __restrict__ qT,
    const unsigned short* __restrict__ kT,
    const unsigned short* __restrict__ v2,
    const float* __restrict__ mask,
    const float* __restrict__ Wo, const float* __restrict__ bo,
    float* __restrict__ out, int L)
{
    __shared__ float mrg[64 * 9];

    const int tid  = threadIdx.x;
    const int lane = tid & 63;
    const int h    = tid >> 6;          // wave parity within pair
    const int lo   = lane & 15;
    const int quad = lane >> 4;

    // LPT + XCD affinity: id = (31-s)*128 + w  ->  long waves first, id%8==w%8
    const int id = blockIdx.x;
    const int w  = id & 127;
    const int s  = 31 - (id >> 7);
    const int wq0 = w * BLK + s * 16;

    const int kstart = max(0, w * BLK - HALF);
    const int n      = ((wq0 + 15 - kstart) >> 6) + 1;   // total 64-key chunks
    const int myq    = wq0 + lo;

    // Q B-frag: B[k=c][n=q]
    const bf16x8 qB = *(const bf16x8*)(qT + (size_t)myq * C + quad * 8);

    const f32x4 zero = {0.f, 0.f, 0.f, 0.f};
    f32x4 O0 = zero, O1 = zero;
    float psum = 0.f;

    const int qsl = lo + 16 * ((quad & 1) << 1);

    // ---- full chunks (no causal masking) ----
    for (int j = h; j < n - 1; j += 2) {
        const int kb = kstart + (j << 6);

        f32x4 S[4];
        float4 fm4[4];
        const unsigned short* kp = kT + (size_t)(kb + lo) * C + quad * 8;
        #pragma unroll
        for (int t = 0; t < 4; ++t) {
            const bf16x8 kA = *(const bf16x8*)(kp + (size_t)(t * 16) * C);
            S[t] = __builtin_amdgcn_mfma_f32_16x16x32_bf16(kA, qB, zero, 0, 0, 0);
            fm4[t] = *(const float4*)(mask + kb + t * 16 + quad * 4);
        }

        unsigned wp[4][2];
        #pragma unroll
        for (int t = 0; t < 4; ++t) {
            const float* fmp = (const float*)&fm4[t];
            float p[4];
            #pragma unroll
            for (int r = 0; r < 4; ++r) {
                const float pd = __expf(S[t][r]) * (fmp[r] + 1e-9f);
                psum += pd;
                p[r] = pd * fmp[r];
            }
            wp[t][0] = pk2(p[0], p[1]);
            wp[t][1] = pk2(p[2], p[3]);
        }

        const unsigned short* vbase = v2 + ((size_t)(kb >> 6) << 11);
        #pragma unroll
        for (int g = 0; g < 2; ++g) {
            union { int i[4]; bf16x8 v; } pb;
            #pragma unroll
            for (int i = 0; i < 4; ++i) {
                const int src = qsl + 16 * (i >> 1);
                const int v0 = __shfl((int)wp[2 * g][i & 1], src);
                const int v1 = __shfl((int)wp[2 * g + 1][i & 1], src);
                pb.i[i] = (quad < 2) ? v0 : v1;
            }
            const bf16x8 vA0 = *(const bf16x8*)(vbase + g * 1024 + lo * 32 + quad * 8);
            const bf16x8 vA1 = *(const bf16x8*)(vbase + g * 1024 + (16 + lo) * 32 + quad * 8);
            O0 = __builtin_amdgcn_mfma_f32_16x16x32_bf16(vA0, pb.v, O0, 0, 0, 0);
            O1 = __builtin_amdgcn_mfma_f32_16x16x32_bf16(vA1, pb.v, O1, 0, 0, 0);
        }
    }

    // ---- the single causal chunk (owner: parity of n-1) ----
    if (((n - 1) & 1) == h) {
        const int kb = kstart + ((n - 1) << 6);

        f32x4 S[4];
        float4 fm4[4];
        const unsigned short* kp = kT + (size_t)(kb + lo) * C + quad * 8;
        #pragma unroll
        for (int t = 0; t < 4; ++t) {
            const bf16x8 kA = *(const bf16x8*)(kp + (size_t)(t * 16) * C);
            S[t] = __builtin_amdgcn_mfma_f32_16x16x32_bf16(kA, qB, zero, 0, 0, 0);
            fm4[t] = *(const float4*)(mask + kb + t * 16 + quad * 4);
        }

        unsigned wp[4][2];
        #pragma unroll
        for (int t = 0; t < 4; ++t) {
            const float* fmp = (const float*)&fm4[t];
            float p[4];
            #pragma unroll
            for (int r = 0; r < 4; ++r) {
                const int key = kb + t * 16 + quad * 4 + r;
                const float pd = (key <= myq) ? __expf(S[t][r]) * (fmp[r] + 1e-9f) : 0.f;
                psum += pd;
                p[r] = pd * fmp[r];
            }
            wp[t][0] = pk2(p[0], p[1]);
            wp[t][1] = pk2(p[2], p[3]);
        }

        const unsigned short* vbase = v2 + ((size_t)(kb >> 6) << 11);
        #pragma unroll
        for (int g = 0; g < 2; ++g) {
            union { int i[4]; bf16x8 v; } pb;
            #pragma unroll
            for (int i = 0; i < 4; ++i) {
                const int src = qsl + 16 * (i >> 1);
                const int v0 = __shfl((int)wp[2 * g][i & 1], src);
                const int v1 = __shfl((int)wp[2 * g + 1][i & 1], src);
                pb.i[i] = (quad < 2) ? v0 : v1;
            }
            const bf16x8 vA0 = *(const bf16x8*)(vbase + g * 1024 + lo * 32 + quad * 8);
            const bf16x8 vA1 = *(const bf16x8*)(vbase + g * 1024 + (16 + lo) * 32 + quad * 8);
            O0 = __builtin_amdgcn_mfma_f32_16x16x32_bf16(vA0, pb.v, O0, 0, 0, 0);
            O1 = __builtin_amdgcn_mfma_f32_16x16x32_bf16(vA1, pb.v, O1, 0, 0, 0);
        }
    }

    // ---- merge wave1 partials into wave0 ----
    if (h == 1) {
        #pragma unroll
        for (int r = 0; r < 4; ++r) {
            mrg[lane * 9 + r]     = O0[r];
            mrg[lane * 9 + 4 + r] = O1[r];
        }
        mrg[lane * 9 + 8] = psum;
    }
    __syncthreads();
    if (h == 1) return;

    #pragma unroll
    for (int r = 0; r < 4; ++r) {
        O0[r] += mrg[lane * 9 + r];
        O1[r] += mrg[lane * 9 + 4 + r];
    }
    psum += mrg[lane * 9 + 8];

    // ---- denominator across quads for each query col ----
    float dsum = psum;
    dsum += __shfl_xor(dsum, 16);
    dsum += __shfl_xor(dsum, 32);
    const float inv = 1.f / dsum;

    // ---- epilogue: T = relu(O^T*inv) -> B-layout via quad-permute ----
    unsigned tw[2][2];
    tw[0][0] = pk2(fmaxf(O0[0] * inv, 0.f), fmaxf(O0[1] * inv, 0.f));
    tw[0][1] = pk2(fmaxf(O0[2] * inv, 0.f), fmaxf(O0[3] * inv, 0.f));
    tw[1][0] = pk2(fmaxf(O1[0] * inv, 0.f), fmaxf(O1[1] * inv, 0.f));
    tw[1][1] = pk2(fmaxf(O1[2] * inv, 0.f), fmaxf(O1[3] * inv, 0.f));

    union { int i[4]; bf16x8 v; } tb;
    #pragma unroll
    for (int i = 0; i < 4; ++i) {
        const int src = qsl + 16 * (i >> 1);
        const int v0 = __shfl((int)tw[0][i & 1], src);
        const int v1 = __shfl((int)tw[1][i & 1], src);
        tb.i[i] = (quad < 2) ? v0 : v1;
    }

    const float mk = mask[myq];
    #pragma unroll
    for (int t = 0; t < 4; ++t) {
        float wtmp[8];
        *(float4*)&wtmp[0] = *(const float4*)(Wo + (size_t)(t * 16 + lo) * C + quad * 8);
        *(float4*)&wtmp[4] = *(const float4*)(Wo + (size_t)(t * 16 + lo) * C + quad * 8 + 4);
        union { unsigned u[4]; bf16x8 v; } wo;
        #pragma unroll
        for (int i = 0; i < 4; ++i) wo.u[i] = pk2(wtmp[2 * i], wtmp[2 * i + 1]);
        const f32x4 R = __builtin_amdgcn_mfma_f32_16x16x32_bf16(wo.v, tb.v, zero, 0, 0, 0);
        const float4 bo4 = *(const float4*)(bo + t * 16 + quad * 4);
        const float* bop = (const float*)&bo4;
        #pragma unroll
        for (int r = 0; r < 4; ++r)
            out[(size_t)(t * 16 + quad * 4 + r) * L + myq] = (R[r] + bop[r]) * mk;
    }
}

extern "C" void kernel_launch(void* const* d_in, const int* in_sizes, int n_in,
                              void* d_out, int out_size, void* d_ws, size_t ws_size,
                              hipStream_t stream)
{
    const float* x1   = (const float*)d_in[0];
    // d_in[1] = x2 : unused (encoder stage)
    const float* mask = (const float*)d_in[2];
    const float* Wq   = (const float*)d_in[3];
    const float* bq   = (const float*)d_in[4];
    const float* Wk   = (const float*)d_in[5];
    const float* bk   = (const float*)d_in[6];
    const float* Wv   = (const float*)d_in[7];
    const float* bv   = (const float*)d_in[8];
    const float* Wo   = (const float*)d_in[9];
    const float* bo   = (const float*)d_in[10];
    float* out = (float*)d_out;

    const int L = in_sizes[0] / QD;                  // 65536
    unsigned short* qT = (unsigned short*)d_ws;      // L*32 bf16
    unsigned short* kT = qT + (size_t)L * C;         // L*32 bf16
    unsigned short* v2 = kT + (size_t)L * C;         // L*32 bf16 (tiled)

    hipLaunchKernelGGL(qkv_proj, dim3(L / 256, 3), dim3(256), 0, stream,
                       x1, Wq, bq, Wk, bk, Wv, bv, qT, kT, v2, L);

    // one wg per 16-query tile: L/16 = 4096 wgs (2 waves each, split-K)
    hipLaunchKernelGGL(att_kernel, dim3(L / 16), dim3(128), 0, stream,
                       qT, kT, v2, mask, Wo, bo, out, L);
}